// Round 1
// baseline (1077.117 us; speedup 1.0000x reference)
//
#include <hip/hip_runtime.h>
#include <math.h>

#define N_NODES 50000
#define N_EDGES 800000
#define NGRAPH  512
#define BN_EPS  1e-5f

// ---------------- degree / dinv ----------------
__global__ void k_deg(const int* __restrict__ dst, float* __restrict__ deg) {
    int e = blockIdx.x * blockDim.x + threadIdx.x;
    if (e < N_EDGES) atomicAdd(&deg[dst[e]], 1.0f);
}

__global__ void k_dinv(float* __restrict__ deg) {
    int n = blockIdx.x * blockDim.x + threadIdx.x;
    if (n < N_NODES) deg[n] = rsqrtf(deg[n] + 1.0f);
}

// ---------------- layer-1 aggregation on 4 input channels ----------------
__global__ void k_self1(const float4* __restrict__ x, const float* __restrict__ dinv,
                        float4* __restrict__ aggx) {
    int n = blockIdx.x * blockDim.x + threadIdx.x;
    if (n < N_NODES) {
        float di = dinv[n], c = di * di;
        float4 v = x[n];
        v.x *= c; v.y *= c; v.z *= c; v.w *= c;
        aggx[n] = v;
    }
}

__global__ void k_edge1(const int* __restrict__ src, const int* __restrict__ dst,
                        const float* __restrict__ dinv, const float4* __restrict__ x,
                        float* __restrict__ aggx) {
    int e = blockIdx.x * blockDim.x + threadIdx.x;
    if (e >= N_EDGES) return;
    int s = src[e], t = dst[e];
    float c = dinv[s] * dinv[t];
    float4 v = x[s];
    atomicAdd(&aggx[t * 4 + 0], v.x * c);
    atomicAdd(&aggx[t * 4 + 1], v.y * c);
    atomicAdd(&aggx[t * 4 + 2], v.z * c);
    atomicAdd(&aggx[t * 4 + 3], v.w * c);
}

// ---------------- BN1 stats (h1 recomputed on the fly, never stored) --------
__global__ __launch_bounds__(128) void k_stats1(const float4* __restrict__ aggx,
        const float* __restrict__ W1, const float* __restrict__ b1,
        float* __restrict__ s1, float* __restrict__ q1) {
    __shared__ float w1s[4][128];
    int j = threadIdx.x;
    for (int c = 0; c < 4; c++) w1s[c][j] = W1[c * 128 + j];
    float bj = b1[j];
    __syncthreads();
    int per = (N_NODES + gridDim.x - 1) / gridDim.x;
    int n0 = blockIdx.x * per, n1 = min(n0 + per, N_NODES);
    float ps = 0.f, pq = 0.f;
    for (int n = n0; n < n1; n++) {
        float4 a = aggx[n];
        float h = fmaf(a.x, w1s[0][j], fmaf(a.y, w1s[1][j],
                  fmaf(a.z, w1s[2][j], fmaf(a.w, w1s[3][j], bj))));
        h = fmaxf(h, 0.f);
        ps += h; pq += h * h;
    }
    atomicAdd(&s1[j], ps);
    atomicAdd(&q1[j], pq);
}

// ---------------- fold BN1 into W2 -> W2f, d2 ----------------
__global__ __launch_bounds__(128) void k_fold1(const float* __restrict__ s1,
        const float* __restrict__ q1, const float* __restrict__ g1,
        const float* __restrict__ be1, const float* __restrict__ W2,
        float* __restrict__ W2f, float* __restrict__ d2) {
    __shared__ float a[128], c[128];
    int t = threadIdx.x;
    {
        float mean = s1[t] / (float)N_NODES;
        float var  = q1[t] / (float)N_NODES - mean * mean;
        float aa   = rsqrtf(var + BN_EPS) * g1[t];
        a[t] = aa;
        c[t] = be1[t] - mean * aa;
    }
    __syncthreads();
    if (t < 64) {
        float dd = 0.f;
        for (int k = 0; k < 128; k++) {
            float wv = W2[k * 64 + t];
            W2f[k * 64 + t] = a[k] * wv;
            dd = fmaf(c[k], wv, dd);
        }
        d2[t] = dd;
    }
}

// ------- fused: recompute h1 tile from aggx, GEMM vs W2f, self-term init ----
__global__ __launch_bounds__(256) void k_h2(const float4* __restrict__ aggx,
        const float* __restrict__ W1, const float* __restrict__ b1,
        const float* __restrict__ W2f, const float* __restrict__ d2,
        const float* __restrict__ dinv,
        float* __restrict__ h2, float* __restrict__ agg2) {
    __shared__ float w[128 * 64];
    __shared__ float hs[16][128];
    __shared__ float w1s[4][128];
    __shared__ float b1s[128];
    int tid = threadIdx.x;
    for (int i = tid; i < 8192; i += 256) w[i] = W2f[i];
    if (tid < 128) {
        b1s[tid] = b1[tid];
        for (int c = 0; c < 4; c++) w1s[c][tid] = W1[c * 128 + tid];
    }
    __syncthreads();
    int n0 = blockIdx.x * 16;   // grid is exactly N_NODES/16
    for (int i = tid; i < 2048; i += 256) {
        int nn = n0 + (i >> 7), j = i & 127;
        float4 a = aggx[nn];
        float h = fmaf(a.x, w1s[0][j], fmaf(a.y, w1s[1][j],
                  fmaf(a.z, w1s[2][j], fmaf(a.w, w1s[3][j], b1s[j]))));
        hs[i >> 7][j] = fmaxf(h, 0.f);
    }
    __syncthreads();
    int j = tid & 63, q = tid >> 6;
    float acc0 = 0.f, acc1 = 0.f, acc2 = 0.f, acc3 = 0.f;
    for (int k = 0; k < 128; k++) {
        float wv = w[k * 64 + j];
        acc0 = fmaf(hs[q * 4 + 0][k], wv, acc0);
        acc1 = fmaf(hs[q * 4 + 1][k], wv, acc1);
        acc2 = fmaf(hs[q * 4 + 2][k], wv, acc2);
        acc3 = fmaf(hs[q * 4 + 3][k], wv, acc3);
    }
    float dj = d2[j];
    float av[4] = {acc0, acc1, acc2, acc3};
#pragma unroll
    for (int i = 0; i < 4; i++) {
        int n = n0 + q * 4 + i;
        float v = av[i] + dj;
        float di = dinv[n];
        h2[n * 64 + j]   = v;
        agg2[n * 64 + j] = v * di * di;
    }
}

// ---------------- layer-2 edge scatter: 16 lanes per edge ----------------
__global__ void k_edge2(const int* __restrict__ src, const int* __restrict__ dst,
                        const float* __restrict__ dinv, const float4* __restrict__ h2,
                        float* __restrict__ agg2) {
    int t = blockIdx.x * blockDim.x + threadIdx.x;
    int e = t >> 4;
    if (e >= N_EDGES) return;
    int c4 = t & 15;
    int s = src[e], d = dst[e];
    float c = dinv[s] * dinv[d];
    float4 v = h2[s * 16 + c4];
    float* out = agg2 + d * 64 + c4 * 4;
    atomicAdd(out + 0, v.x * c);
    atomicAdd(out + 1, v.y * c);
    atomicAdd(out + 2, v.z * c);
    atomicAdd(out + 3, v.w * c);
}

// ---------------- relu(agg2 + b2) + BN2 stats ----------------
__global__ __launch_bounds__(256) void k_out2(const float* __restrict__ agg2,
        const float* __restrict__ b2, float* __restrict__ out2,
        float* __restrict__ s2, float* __restrict__ q2) {
    int j = threadIdx.x & 63;
    float bj = b2[j];
    float ps = 0.f, pq = 0.f;
    for (int n = blockIdx.x * 4 + (threadIdx.x >> 6); n < N_NODES; n += gridDim.x * 4) {
        float v = fmaxf(agg2[n * 64 + j] + bj, 0.f);
        out2[n * 64 + j] = v;
        ps += v; pq += v * v;
    }
    atomicAdd(&s2[j], ps);
    atomicAdd(&q2[j], pq);
}

// ---------------- generic BN affine params from stats ----------------
__global__ void k_bnparam(const float* __restrict__ s, const float* __restrict__ q,
                          const float* __restrict__ g, const float* __restrict__ be,
                          float* __restrict__ A, float* __restrict__ C, float inv_cnt) {
    int j = threadIdx.x;
    float mean = s[j] * inv_cnt;
    float var  = q[j] * inv_cnt - mean * mean;
    float a = rsqrtf(var + BN_EPS) * g[j];
    A[j] = a;
    C[j] = be[j] - mean * a;
}

// ---------------- global_add_pool (batch is sorted: run-accumulate) ---------
__global__ __launch_bounds__(64) void k_pool(const float* __restrict__ out2,
        const int* __restrict__ batch, const float* __restrict__ A2,
        const float* __restrict__ C2, float* __restrict__ hg) {
    int j = threadIdx.x;
    float a = A2[j], c = C2[j];
    int per = (N_NODES + gridDim.x - 1) / gridDim.x;
    int n0 = blockIdx.x * per, n1 = min(n0 + per, N_NODES);
    float acc = 0.f;
    int cur = -1;
    for (int n = n0; n < n1; n++) {
        int g = batch[n];
        float v = fmaf(out2[n * 64 + j], a, c);
        if (g != cur) {
            if (cur >= 0) atomicAdd(&hg[cur * 64 + j], acc);
            cur = g; acc = v;
        } else {
            acc += v;
        }
    }
    if (cur >= 0) atomicAdd(&hg[cur * 64 + j], acc);
}

// ---------------- fc1 + relu + BN3 stats ----------------
__global__ __launch_bounds__(256) void k_fc1(const float* __restrict__ hg,
        const float* __restrict__ fW1, const float* __restrict__ fb1,
        float* __restrict__ t1, float* __restrict__ s3, float* __restrict__ q3) {
    __shared__ float w[64 * 64];
    int tid = threadIdx.x;
    for (int i = tid; i < 4096; i += 256) w[i] = fW1[i];
    __syncthreads();
    int j = tid & 63, q = tid >> 6;
    float bj = fb1[j];
    float ps = 0.f, pq = 0.f;
    for (int r = blockIdx.x * 4 + q; r < NGRAPH; r += gridDim.x * 4) {
        float acc = bj;
        for (int k = 0; k < 64; k++) acc = fmaf(hg[r * 64 + k], w[k * 64 + j], acc);
        acc = fmaxf(acc, 0.f);
        t1[r * 64 + j] = acc;
        ps += acc; pq += acc * acc;
    }
    atomicAdd(&s3[j], ps);
    atomicAdd(&q3[j], pq);
}

// ---------------- bn3 -> fc2 + relu -> fc3 -> log_softmax ----------------
__global__ __launch_bounds__(256) void k_final(const float* __restrict__ t1,
        const float* __restrict__ A3, const float* __restrict__ C3,
        const float* __restrict__ fW2, const float* __restrict__ fb2,
        const float* __restrict__ fW3, const float* __restrict__ fb3,
        float* __restrict__ out) {
    __shared__ float w2[64 * 64];
    __shared__ float w3s[192];
    __shared__ float a3[64], c3[64], b3s[3];
    int tid = threadIdx.x;
    for (int i = tid; i < 4096; i += 256) w2[i] = fW2[i];
    if (tid < 192) w3s[tid] = fW3[tid];
    if (tid < 64) { a3[tid] = A3[tid]; c3[tid] = C3[tid]; }
    if (tid < 3)  b3s[tid] = fb3[tid];
    __syncthreads();
    int lane = tid & 63, wv = tid >> 6;
    float fbj = fb2[lane];
    for (int r = blockIdx.x * 4 + wv; r < NGRAPH; r += gridDim.x * 4) {
        float acc = fbj;
        for (int k = 0; k < 64; k++) {
            float xk = fmaf(t1[r * 64 + k], a3[k], c3[k]);
            acc = fmaf(xk, w2[k * 64 + lane], acc);
        }
        acc = fmaxf(acc, 0.f);
        float o0 = acc * w3s[lane * 3 + 0];
        float o1 = acc * w3s[lane * 3 + 1];
        float o2 = acc * w3s[lane * 3 + 2];
        for (int off = 32; off; off >>= 1) {
            o0 += __shfl_down(o0, off);
            o1 += __shfl_down(o1, off);
            o2 += __shfl_down(o2, off);
        }
        if (lane == 0) {
            o0 += b3s[0]; o1 += b3s[1]; o2 += b3s[2];
            float m = fmaxf(o0, fmaxf(o1, o2));
            float lse = m + logf(expf(o0 - m) + expf(o1 - m) + expf(o2 - m));
            out[r * 3 + 0] = o0 - lse;
            out[r * 3 + 1] = o1 - lse;
            out[r * 3 + 2] = o2 - lse;
        }
    }
}

extern "C" void kernel_launch(void* const* d_in, const int* in_sizes, int n_in,
                              void* d_out, int out_size, void* d_ws, size_t ws_size,
                              hipStream_t stream) {
    const float* x   = (const float*)d_in[0];
    const int*   ei  = (const int*)d_in[1];
    const int*   bat = (const int*)d_in[2];
    const float* W1  = (const float*)d_in[3];
    const float* b1  = (const float*)d_in[4];
    const float* g1  = (const float*)d_in[5];
    const float* be1 = (const float*)d_in[6];
    const float* W2  = (const float*)d_in[7];
    const float* b2  = (const float*)d_in[8];
    const float* g2  = (const float*)d_in[9];
    const float* be2 = (const float*)d_in[10];
    const float* fW1 = (const float*)d_in[11];
    const float* fb1 = (const float*)d_in[12];
    const float* g3  = (const float*)d_in[13];
    const float* be3 = (const float*)d_in[14];
    const float* fW2 = (const float*)d_in[15];
    const float* fb2 = (const float*)d_in[16];
    const float* fW3 = (const float*)d_in[17];
    const float* fb3 = (const float*)d_in[18];

    float* ws = (float*)d_ws;
    // ---- zeroed region (one memset): deg | hg | s1 q1 s2 q2 s3 q3 ----
    float* deg = ws;                       // N
    float* hg  = deg + N_NODES;            // 512*64
    float* s1  = hg + NGRAPH * 64;         // 128
    float* q1  = s1 + 128;                 // 128
    float* s2  = q1 + 128;                 // 64
    float* q2  = s2 + 64;                  // 64
    float* s3  = q2 + 64;                  // 64
    float* q3  = s3 + 64;                  // 64
    size_t zero_floats = (size_t)N_NODES + NGRAPH * 64 + 512;
    // ---- non-zeroed scratch ----
    float* aggx = q3 + 64;                 // N*4   (offset 83280, 16B aligned)
    float* h2   = aggx + (size_t)N_NODES * 4;   // N*64
    float* agg2 = h2 + (size_t)N_NODES * 64;    // N*64
    float* W2f  = agg2 + (size_t)N_NODES * 64;  // 128*64
    float* d2   = W2f + 128 * 64;          // 64
    float* A2   = d2 + 64;                 // 64
    float* C2   = A2 + 64;                 // 64
    float* A3   = C2 + 64;                 // 64
    float* C3   = A3 + 64;                 // 64
    float* t1   = C3 + 64;                 // 512*64
    float* out2 = h2;                      // alias: h2 dead after k_edge2

    hipMemsetAsync(d_ws, 0, zero_floats * sizeof(float), stream);

    const int* src = ei;
    const int* dst = ei + N_EDGES;

    k_deg  <<<(N_EDGES + 255) / 256, 256, 0, stream>>>(dst, deg);
    k_dinv <<<(N_NODES + 255) / 256, 256, 0, stream>>>(deg);
    k_self1<<<(N_NODES + 255) / 256, 256, 0, stream>>>((const float4*)x, deg, (float4*)aggx);
    k_edge1<<<(N_EDGES + 255) / 256, 256, 0, stream>>>(src, dst, deg, (const float4*)x, aggx);
    k_stats1<<<512, 128, 0, stream>>>((const float4*)aggx, W1, b1, s1, q1);
    k_fold1<<<1, 128, 0, stream>>>(s1, q1, g1, be1, W2, W2f, d2);
    k_h2   <<<N_NODES / 16, 256, 0, stream>>>((const float4*)aggx, W1, b1, W2f, d2, deg, h2, agg2);
    k_edge2<<<(N_EDGES * 16) / 256, 256, 0, stream>>>(src, dst, deg, (const float4*)h2, agg2);
    k_out2 <<<512, 256, 0, stream>>>(agg2, b2, out2, s2, q2);
    k_bnparam<<<1, 64, 0, stream>>>(s2, q2, g2, be2, A2, C2, 1.0f / (float)N_NODES);
    k_pool <<<512, 64, 0, stream>>>(out2, bat, A2, C2, hg);
    k_fc1  <<<16, 256, 0, stream>>>(hg, fW1, fb1, t1, s3, q3);
    k_bnparam<<<1, 64, 0, stream>>>(s3, q3, g3, be3, A3, C3, 1.0f / (float)NGRAPH);
    k_final<<<16, 256, 0, stream>>>(t1, A3, C3, fW2, fb2, fW3, fb3, (float*)d_out);
}

// Round 2
// 388.898 us; speedup vs baseline: 2.7697x; 2.7697x over previous
//
#include <hip/hip_runtime.h>
#include <math.h>

#define N_NODES 50000
#define N_EDGES 800000
#define NGRAPH  512
#define BN_EPS  1e-5f

// ---------------- degree count (int) ----------------
__global__ void k_deg(const int* __restrict__ dst, int* __restrict__ cnt) {
    int e = blockIdx.x * blockDim.x + threadIdx.x;
    if (e < N_EDGES) atomicAdd(&cnt[dst[e]], 1);
}

__global__ void k_dinv(const int* __restrict__ cnt, float* __restrict__ dinv) {
    int n = blockIdx.x * blockDim.x + threadIdx.x;
    if (n < N_NODES) dinv[n] = rsqrtf((float)cnt[n] + 1.0f);
}

// ---------------- exclusive prefix sum over 50000 counts (1 block) ---------
__global__ __launch_bounds__(1024) void k_scan(const int* __restrict__ cnt,
                                               int* __restrict__ row_start) {
    __shared__ int part[1024];
    const int CH = 49;                       // 1024*49 = 50176 >= 50000
    int t = threadIdx.x;
    int base = t * CH;
    int s = 0;
    for (int i = 0; i < CH; i++) {
        int n = base + i;
        if (n < N_NODES) s += cnt[n];
    }
    part[t] = s;
    __syncthreads();
    for (int off = 1; off < 1024; off <<= 1) {
        int v = (t >= off) ? part[t - off] : 0;
        __syncthreads();
        if (t >= off) part[t] += v;
        __syncthreads();
    }
    int run = (t == 0) ? 0 : part[t - 1];
    for (int i = 0; i < CH; i++) {
        int n = base + i;
        if (n < N_NODES) { row_start[n] = run; run += cnt[n]; }
    }
}

// ---------------- CSR fill: entry = {src, coef} ----------------
__global__ void k_fill(const int* __restrict__ src, const int* __restrict__ dst,
                       const int* __restrict__ row_start, int* __restrict__ cursor,
                       const float* __restrict__ dinv, int2* __restrict__ entries) {
    int e = blockIdx.x * blockDim.x + threadIdx.x;
    if (e >= N_EDGES) return;
    int s = src[e], t = dst[e];
    int pos = row_start[t] + atomicAdd(&cursor[t], 1);
    entries[pos] = make_int2(s, __float_as_int(dinv[s] * dinv[t]));
}

// ---------------- layer-1 gather (4 channels) + self term ----------------
__global__ void k_gather1(const int* __restrict__ row_start, const int* __restrict__ cnt,
                          const int2* __restrict__ entries, const float* __restrict__ dinv,
                          const float4* __restrict__ x, float4* __restrict__ aggx) {
    int n = blockIdx.x * blockDim.x + threadIdx.x;
    if (n >= N_NODES) return;
    float di = dinv[n], c = di * di;
    float4 a = x[n];
    float4 acc = make_float4(a.x * c, a.y * c, a.z * c, a.w * c);
    int rs = row_start[n], cn = cnt[n];
    const int2* ep = entries + rs;
    for (int i = 0; i < cn; i++) {
        int2 e = ep[i];
        float co = __int_as_float(e.y);
        float4 v = x[e.x];
        acc.x = fmaf(v.x, co, acc.x);
        acc.y = fmaf(v.y, co, acc.y);
        acc.z = fmaf(v.z, co, acc.z);
        acc.w = fmaf(v.w, co, acc.w);
    }
    aggx[n] = acc;
}

// ---------------- BN1 stats (h1 recomputed on the fly, never stored) --------
__global__ __launch_bounds__(128) void k_stats1(const float4* __restrict__ aggx,
        const float* __restrict__ W1, const float* __restrict__ b1,
        float* __restrict__ s1, float* __restrict__ q1) {
    __shared__ float w1s[4][128];
    int j = threadIdx.x;
    for (int c = 0; c < 4; c++) w1s[c][j] = W1[c * 128 + j];
    float bj = b1[j];
    __syncthreads();
    int per = (N_NODES + gridDim.x - 1) / gridDim.x;
    int n0 = blockIdx.x * per, n1 = min(n0 + per, N_NODES);
    float ps = 0.f, pq = 0.f;
    for (int n = n0; n < n1; n++) {
        float4 a = aggx[n];
        float h = fmaf(a.x, w1s[0][j], fmaf(a.y, w1s[1][j],
                  fmaf(a.z, w1s[2][j], fmaf(a.w, w1s[3][j], bj))));
        h = fmaxf(h, 0.f);
        ps += h; pq += h * h;
    }
    atomicAdd(&s1[j], ps);
    atomicAdd(&q1[j], pq);
}

// ---------------- fold BN1 into W2 -> W2f, d2 ----------------
__global__ __launch_bounds__(128) void k_fold1(const float* __restrict__ s1,
        const float* __restrict__ q1, const float* __restrict__ g1,
        const float* __restrict__ be1, const float* __restrict__ W2,
        float* __restrict__ W2f, float* __restrict__ d2) {
    __shared__ float a[128], c[128];
    int t = threadIdx.x;
    {
        float mean = s1[t] / (float)N_NODES;
        float var  = q1[t] / (float)N_NODES - mean * mean;
        float aa   = rsqrtf(var + BN_EPS) * g1[t];
        a[t] = aa;
        c[t] = be1[t] - mean * aa;
    }
    __syncthreads();
    if (t < 64) {
        float dd = 0.f;
        for (int k = 0; k < 128; k++) {
            float wv = W2[k * 64 + t];
            W2f[k * 64 + t] = a[k] * wv;
            dd = fmaf(c[k], wv, dd);
        }
        d2[t] = dd;
    }
}

// ------- fused: recompute h1 tile from aggx, GEMM vs W2f -> h2 ----
__global__ __launch_bounds__(256) void k_h2(const float4* __restrict__ aggx,
        const float* __restrict__ W1, const float* __restrict__ b1,
        const float* __restrict__ W2f, const float* __restrict__ d2,
        float* __restrict__ h2) {
    __shared__ float w[128 * 64];
    __shared__ float hs[16][128];
    __shared__ float w1s[4][128];
    __shared__ float b1s[128];
    int tid = threadIdx.x;
    for (int i = tid; i < 8192; i += 256) w[i] = W2f[i];
    if (tid < 128) {
        b1s[tid] = b1[tid];
        for (int c = 0; c < 4; c++) w1s[c][tid] = W1[c * 128 + tid];
    }
    __syncthreads();
    int n0 = blockIdx.x * 16;   // grid is exactly N_NODES/16
    for (int i = tid; i < 2048; i += 256) {
        int nn = n0 + (i >> 7), j = i & 127;
        float4 a = aggx[nn];
        float h = fmaf(a.x, w1s[0][j], fmaf(a.y, w1s[1][j],
                  fmaf(a.z, w1s[2][j], fmaf(a.w, w1s[3][j], b1s[j]))));
        hs[i >> 7][j] = fmaxf(h, 0.f);
    }
    __syncthreads();
    int j = tid & 63, q = tid >> 6;
    float acc0 = 0.f, acc1 = 0.f, acc2 = 0.f, acc3 = 0.f;
    for (int k = 0; k < 128; k++) {
        float wv = w[k * 64 + j];
        acc0 = fmaf(hs[q * 4 + 0][k], wv, acc0);
        acc1 = fmaf(hs[q * 4 + 1][k], wv, acc1);
        acc2 = fmaf(hs[q * 4 + 2][k], wv, acc2);
        acc3 = fmaf(hs[q * 4 + 3][k], wv, acc3);
    }
    float dj = d2[j];
    float av[4] = {acc0, acc1, acc2, acc3};
#pragma unroll
    for (int i = 0; i < 4; i++) {
        int n = n0 + q * 4 + i;
        h2[n * 64 + j] = av[i] + dj;
    }
}

// ------- layer-2 gather: 1 wave per node, lane=channel; fused relu+b2+stats -
__global__ __launch_bounds__(256) void k_gather2(const int* __restrict__ row_start,
        const int* __restrict__ cnt, const int2* __restrict__ entries,
        const float* __restrict__ dinv, const float* __restrict__ h2,
        const float* __restrict__ b2, float* __restrict__ out2,
        float* __restrict__ s2, float* __restrict__ q2) {
    int j = threadIdx.x & 63;
    int w = threadIdx.x >> 6;
    float bj = b2[j];
    float ps = 0.f, pq = 0.f;
    for (int n = blockIdx.x * 4 + w; n < N_NODES; n += gridDim.x * 4) {
        int rs = row_start[n], cn = cnt[n];
        float di = dinv[n];
        float acc = h2[n * 64 + j] * di * di;
        const int2* ep = entries + rs;
        int i = 0;
        for (; i + 1 < cn; i += 2) {
            int2 e0 = ep[i], e1 = ep[i + 1];
            float v0 = h2[e0.x * 64 + j];
            float v1 = h2[e1.x * 64 + j];
            acc = fmaf(v0, __int_as_float(e0.y), acc);
            acc = fmaf(v1, __int_as_float(e1.y), acc);
        }
        if (i < cn) {
            int2 e = ep[i];
            acc = fmaf(h2[e.x * 64 + j], __int_as_float(e.y), acc);
        }
        float v = fmaxf(acc + bj, 0.f);
        out2[n * 64 + j] = v;
        ps += v; pq += v * v;
    }
    __shared__ float ssum[64], sq[64];
    if (threadIdx.x < 64) { ssum[threadIdx.x] = 0.f; sq[threadIdx.x] = 0.f; }
    __syncthreads();
    atomicAdd(&ssum[j], ps);
    atomicAdd(&sq[j], pq);
    __syncthreads();
    if (threadIdx.x < 64) {
        atomicAdd(&s2[j], ssum[j]);
        atomicAdd(&q2[j], sq[j]);
    }
}

// ---------------- generic BN affine params from stats ----------------
__global__ void k_bnparam(const float* __restrict__ s, const float* __restrict__ q,
                          const float* __restrict__ g, const float* __restrict__ be,
                          float* __restrict__ A, float* __restrict__ C, float inv_cnt) {
    int j = threadIdx.x;
    float mean = s[j] * inv_cnt;
    float var  = q[j] * inv_cnt - mean * mean;
    float a = rsqrtf(var + BN_EPS) * g[j];
    A[j] = a;
    C[j] = be[j] - mean * a;
}

// ---------------- global_add_pool (batch is sorted: run-accumulate) ---------
__global__ __launch_bounds__(64) void k_pool(const float* __restrict__ out2,
        const int* __restrict__ batch, const float* __restrict__ A2,
        const float* __restrict__ C2, float* __restrict__ hg) {
    int j = threadIdx.x;
    float a = A2[j], c = C2[j];
    int per = (N_NODES + gridDim.x - 1) / gridDim.x;
    int n0 = blockIdx.x * per, n1 = min(n0 + per, N_NODES);
    float acc = 0.f;
    int cur = -1;
    for (int n = n0; n < n1; n++) {
        int g = batch[n];
        float v = fmaf(out2[n * 64 + j], a, c);
        if (g != cur) {
            if (cur >= 0) atomicAdd(&hg[cur * 64 + j], acc);
            cur = g; acc = v;
        } else {
            acc += v;
        }
    }
    if (cur >= 0) atomicAdd(&hg[cur * 64 + j], acc);
}

// ---------------- fc1 + relu + BN3 stats ----------------
__global__ __launch_bounds__(256) void k_fc1(const float* __restrict__ hg,
        const float* __restrict__ fW1, const float* __restrict__ fb1,
        float* __restrict__ t1, float* __restrict__ s3, float* __restrict__ q3) {
    __shared__ float w[64 * 64];
    int tid = threadIdx.x;
    for (int i = tid; i < 4096; i += 256) w[i] = fW1[i];
    __syncthreads();
    int j = tid & 63, q = tid >> 6;
    float bj = fb1[j];
    float ps = 0.f, pq = 0.f;
    for (int r = blockIdx.x * 4 + q; r < NGRAPH; r += gridDim.x * 4) {
        float acc = bj;
        for (int k = 0; k < 64; k++) acc = fmaf(hg[r * 64 + k], w[k * 64 + j], acc);
        acc = fmaxf(acc, 0.f);
        t1[r * 64 + j] = acc;
        ps += acc; pq += acc * acc;
    }
    atomicAdd(&s3[j], ps);
    atomicAdd(&q3[j], pq);
}

// ---------------- bn3 -> fc2 + relu -> fc3 -> log_softmax ----------------
__global__ __launch_bounds__(256) void k_final(const float* __restrict__ t1,
        const float* __restrict__ A3, const float* __restrict__ C3,
        const float* __restrict__ fW2, const float* __restrict__ fb2,
        const float* __restrict__ fW3, const float* __restrict__ fb3,
        float* __restrict__ out) {
    __shared__ float w2[64 * 64];
    __shared__ float w3s[192];
    __shared__ float a3[64], c3[64], b3s[3];
    int tid = threadIdx.x;
    for (int i = tid; i < 4096; i += 256) w2[i] = fW2[i];
    if (tid < 192) w3s[tid] = fW3[tid];
    if (tid < 64) { a3[tid] = A3[tid]; c3[tid] = C3[tid]; }
    if (tid < 3)  b3s[tid] = fb3[tid];
    __syncthreads();
    int lane = tid & 63, wv = tid >> 6;
    float fbj = fb2[lane];
    for (int r = blockIdx.x * 4 + wv; r < NGRAPH; r += gridDim.x * 4) {
        float acc = fbj;
        for (int k = 0; k < 64; k++) {
            float xk = fmaf(t1[r * 64 + k], a3[k], c3[k]);
            acc = fmaf(xk, w2[k * 64 + lane], acc);
        }
        acc = fmaxf(acc, 0.f);
        float o0 = acc * w3s[lane * 3 + 0];
        float o1 = acc * w3s[lane * 3 + 1];
        float o2 = acc * w3s[lane * 3 + 2];
        for (int off = 32; off; off >>= 1) {
            o0 += __shfl_down(o0, off);
            o1 += __shfl_down(o1, off);
            o2 += __shfl_down(o2, off);
        }
        if (lane == 0) {
            o0 += b3s[0]; o1 += b3s[1]; o2 += b3s[2];
            float m = fmaxf(o0, fmaxf(o1, o2));
            float lse = m + logf(expf(o0 - m) + expf(o1 - m) + expf(o2 - m));
            out[r * 3 + 0] = o0 - lse;
            out[r * 3 + 1] = o1 - lse;
            out[r * 3 + 2] = o2 - lse;
        }
    }
}

extern "C" void kernel_launch(void* const* d_in, const int* in_sizes, int n_in,
                              void* d_out, int out_size, void* d_ws, size_t ws_size,
                              hipStream_t stream) {
    const float* x   = (const float*)d_in[0];
    const int*   ei  = (const int*)d_in[1];
    const int*   bat = (const int*)d_in[2];
    const float* W1  = (const float*)d_in[3];
    const float* b1  = (const float*)d_in[4];
    const float* g1  = (const float*)d_in[5];
    const float* be1 = (const float*)d_in[6];
    const float* W2  = (const float*)d_in[7];
    const float* b2  = (const float*)d_in[8];
    const float* g2  = (const float*)d_in[9];
    const float* be2 = (const float*)d_in[10];
    const float* fW1 = (const float*)d_in[11];
    const float* fb1 = (const float*)d_in[12];
    const float* g3  = (const float*)d_in[13];
    const float* be3 = (const float*)d_in[14];
    const float* fW2 = (const float*)d_in[15];
    const float* fb2 = (const float*)d_in[16];
    const float* fW3 = (const float*)d_in[17];
    const float* fb3 = (const float*)d_in[18];

    // ---- workspace layout ----
    // zeroed region: cnt | cursor | hg | s1 q1 s2 q2 s3 q3
    int*   cnt    = (int*)d_ws;                       // N
    int*   cursor = cnt + N_NODES;                    // N
    float* hg     = (float*)(cursor + N_NODES);       // 512*64
    float* s1     = hg + NGRAPH * 64;                 // 128
    float* q1     = s1 + 128;                         // 128
    float* s2     = q1 + 128;                         // 64
    float* q2     = s2 + 64;                          // 64
    float* s3     = q2 + 64;                          // 64
    float* q3     = s3 + 64;                          // 64
    size_t zero_bytes = ((size_t)N_NODES * 2 + NGRAPH * 64 + 512) * 4;
    // non-zeroed scratch
    float* dinv   = q3 + 64;                          // N
    int*   row_start = (int*)(dinv + N_NODES);        // N
    int2*  entries = (int2*)(row_start + N_NODES);    // E (8B each)
    float* aggx   = (float*)(entries + N_EDGES);      // N*4 (16B aligned)
    float* h2     = aggx + (size_t)N_NODES * 4;       // N*64
    float* out2   = h2 + (size_t)N_NODES * 64;        // N*64
    float* W2f    = out2 + (size_t)N_NODES * 64;      // 128*64
    float* d2     = W2f + 128 * 64;                   // 64
    float* A2     = d2 + 64;                          // 64
    float* C2     = A2 + 64;                          // 64
    float* A3     = C2 + 64;                          // 64
    float* C3     = A3 + 64;                          // 64
    float* t1     = C3 + 64;                          // 512*64

    hipMemsetAsync(d_ws, 0, zero_bytes, stream);

    const int* src = ei;
    const int* dst = ei + N_EDGES;

    k_deg    <<<(N_EDGES + 255) / 256, 256, 0, stream>>>(dst, cnt);
    k_dinv   <<<(N_NODES + 255) / 256, 256, 0, stream>>>(cnt, dinv);
    k_scan   <<<1, 1024, 0, stream>>>(cnt, row_start);
    k_fill   <<<(N_EDGES + 255) / 256, 256, 0, stream>>>(src, dst, row_start, cursor, dinv, entries);
    k_gather1<<<(N_NODES + 255) / 256, 256, 0, stream>>>(row_start, cnt, entries, dinv, (const float4*)x, (float4*)aggx);
    k_stats1 <<<512, 128, 0, stream>>>((const float4*)aggx, W1, b1, s1, q1);
    k_fold1  <<<1, 128, 0, stream>>>(s1, q1, g1, be1, W2, W2f, d2);
    k_h2     <<<N_NODES / 16, 256, 0, stream>>>((const float4*)aggx, W1, b1, W2f, d2, h2);
    k_gather2<<<2048, 256, 0, stream>>>(row_start, cnt, entries, dinv, h2, b2, out2, s2, q2);
    k_bnparam<<<1, 64, 0, stream>>>(s2, q2, g2, be2, A2, C2, 1.0f / (float)N_NODES);
    k_pool   <<<1024, 64, 0, stream>>>(out2, bat, A2, C2, hg);
    k_fc1    <<<16, 256, 0, stream>>>(hg, fW1, fb1, t1, s3, q3);
    k_bnparam<<<1, 64, 0, stream>>>(s3, q3, g3, be3, A3, C3, 1.0f / (float)NGRAPH);
    k_final  <<<16, 256, 0, stream>>>(t1, A3, C3, fW2, fb2, fW3, fb3, (float*)d_out);
}

// Round 3
// 308.840 us; speedup vs baseline: 3.4876x; 1.2592x over previous
//
#include <hip/hip_runtime.h>
#include <math.h>

#define N_NODES 50000
#define N_EDGES 800000
#define NGRAPH  512
#define BN_EPS  1e-5f
#define SCAN_BLOCKS 196   // ceil(50000/256)

// ---------------- degree count (int) ----------------
__global__ void k_deg(const int* __restrict__ dst, int* __restrict__ cnt) {
    int e = blockIdx.x * blockDim.x + threadIdx.x;
    if (e < N_EDGES) atomicAdd(&cnt[dst[e]], 1);
}

// ------- scan A: per-256-chunk exclusive scan (coalesced) + dinv fused ------
__global__ __launch_bounds__(256) void k_scanA(const int* __restrict__ cnt,
        float* __restrict__ dinv, int* __restrict__ local, int* __restrict__ bsum) {
    int t = threadIdx.x;
    int n = blockIdx.x * 256 + t;
    int v = 0;
    if (n < N_NODES) {
        v = cnt[n];
        dinv[n] = rsqrtf((float)v + 1.0f);
    }
    __shared__ int sh[256];
    sh[t] = v;
    __syncthreads();
    for (int off = 1; off < 256; off <<= 1) {
        int u = (t >= off) ? sh[t - off] : 0;
        __syncthreads();
        sh[t] += u;
        __syncthreads();
    }
    if (n < N_NODES) local[n] = sh[t] - v;
    if (t == 255) bsum[blockIdx.x] = sh[255];
}

// ------- scan B: exclusive scan of 196 block sums (1 tiny block) ------
__global__ __launch_bounds__(256) void k_scanB(int* __restrict__ bsum) {
    int t = threadIdx.x;
    int v = (t < SCAN_BLOCKS) ? bsum[t] : 0;
    __shared__ int sh[256];
    sh[t] = v;
    __syncthreads();
    for (int off = 1; off < 256; off <<= 1) {
        int u = (t >= off) ? sh[t - off] : 0;
        __syncthreads();
        sh[t] += u;
        __syncthreads();
    }
    if (t < SCAN_BLOCKS) bsum[t] = sh[t] - v;   // exclusive block offsets
}

// ------- scan C: row_start = local + block offset ------
__global__ void k_scanC(const int* __restrict__ local, const int* __restrict__ bsum,
                        int* __restrict__ row_start) {
    int n = blockIdx.x * blockDim.x + threadIdx.x;
    if (n < N_NODES) row_start[n] = local[n] + bsum[n >> 8];
}

// ---------------- CSR fill: entry = {src, coef} ----------------
__global__ void k_fill(const int* __restrict__ src, const int* __restrict__ dst,
                       const int* __restrict__ row_start, int* __restrict__ cursor,
                       const float* __restrict__ dinv, int2* __restrict__ entries) {
    int e = blockIdx.x * blockDim.x + threadIdx.x;
    if (e >= N_EDGES) return;
    int s = src[e], t = dst[e];
    int pos = row_start[t] + atomicAdd(&cursor[t], 1);
    entries[pos] = make_int2(s, __float_as_int(dinv[s] * dinv[t]));
}

// ---------------- layer-1 gather (4 channels) + self term ----------------
__global__ void k_gather1(const int* __restrict__ row_start, const int* __restrict__ cnt,
                          const int2* __restrict__ entries, const float* __restrict__ dinv,
                          const float4* __restrict__ x, float4* __restrict__ aggx) {
    int n = blockIdx.x * blockDim.x + threadIdx.x;
    if (n >= N_NODES) return;
    float di = dinv[n], c = di * di;
    float4 a = x[n];
    float4 acc = make_float4(a.x * c, a.y * c, a.z * c, a.w * c);
    int rs = row_start[n], cn = cnt[n];
    const int2* ep = entries + rs;
    for (int i = 0; i < cn; i++) {
        int2 e = ep[i];
        float co = __int_as_float(e.y);
        float4 v = x[e.x];
        acc.x = fmaf(v.x, co, acc.x);
        acc.y = fmaf(v.y, co, acc.y);
        acc.z = fmaf(v.z, co, acc.z);
        acc.w = fmaf(v.w, co, acc.w);
    }
    aggx[n] = acc;
}

// ---------------- BN1 stats (h1 recomputed on the fly, never stored) --------
__global__ __launch_bounds__(128) void k_stats1(const float4* __restrict__ aggx,
        const float* __restrict__ W1, const float* __restrict__ b1,
        float* __restrict__ s1, float* __restrict__ q1) {
    __shared__ float w1s[4][128];
    int j = threadIdx.x;
    for (int c = 0; c < 4; c++) w1s[c][j] = W1[c * 128 + j];
    float bj = b1[j];
    __syncthreads();
    int per = (N_NODES + gridDim.x - 1) / gridDim.x;
    int n0 = blockIdx.x * per, n1 = min(n0 + per, N_NODES);
    float ps = 0.f, pq = 0.f;
    for (int n = n0; n < n1; n++) {
        float4 a = aggx[n];
        float h = fmaf(a.x, w1s[0][j], fmaf(a.y, w1s[1][j],
                  fmaf(a.z, w1s[2][j], fmaf(a.w, w1s[3][j], bj))));
        h = fmaxf(h, 0.f);
        ps += h; pq += h * h;
    }
    atomicAdd(&s1[j], ps);
    atomicAdd(&q1[j], pq);
}

// ---------------- fold BN1 into W2 -> W2f, d2 ----------------
__global__ __launch_bounds__(128) void k_fold1(const float* __restrict__ s1,
        const float* __restrict__ q1, const float* __restrict__ g1,
        const float* __restrict__ be1, const float* __restrict__ W2,
        float* __restrict__ W2f, float* __restrict__ d2) {
    __shared__ float a[128], c[128];
    int t = threadIdx.x;
    {
        float mean = s1[t] / (float)N_NODES;
        float var  = q1[t] / (float)N_NODES - mean * mean;
        float aa   = rsqrtf(var + BN_EPS) * g1[t];
        a[t] = aa;
        c[t] = be1[t] - mean * aa;
    }
    __syncthreads();
    if (t < 64) {
        float dd = 0.f;
        for (int k = 0; k < 128; k++) {
            float wv = W2[k * 64 + t];
            W2f[k * 64 + t] = a[k] * wv;
            dd = fmaf(c[k], wv, dd);
        }
        d2[t] = dd;
    }
}

// ------- fused: recompute h1 tile from aggx, GEMM vs W2f -> h2 ----
__global__ __launch_bounds__(256) void k_h2(const float4* __restrict__ aggx,
        const float* __restrict__ W1, const float* __restrict__ b1,
        const float* __restrict__ W2f, const float* __restrict__ d2,
        float* __restrict__ h2) {
    __shared__ float w[128 * 64];
    __shared__ float hs[16][128];
    __shared__ float w1s[4][128];
    __shared__ float b1s[128];
    int tid = threadIdx.x;
    for (int i = tid; i < 8192; i += 256) w[i] = W2f[i];
    if (tid < 128) {
        b1s[tid] = b1[tid];
        for (int c = 0; c < 4; c++) w1s[c][tid] = W1[c * 128 + tid];
    }
    __syncthreads();
    int n0 = blockIdx.x * 16;   // grid is exactly N_NODES/16
    for (int i = tid; i < 2048; i += 256) {
        int nn = n0 + (i >> 7), j = i & 127;
        float4 a = aggx[nn];
        float h = fmaf(a.x, w1s[0][j], fmaf(a.y, w1s[1][j],
                  fmaf(a.z, w1s[2][j], fmaf(a.w, w1s[3][j], b1s[j]))));
        hs[i >> 7][j] = fmaxf(h, 0.f);
    }
    __syncthreads();
    int j = tid & 63, q = tid >> 6;
    float acc0 = 0.f, acc1 = 0.f, acc2 = 0.f, acc3 = 0.f;
    for (int k = 0; k < 128; k++) {
        float wv = w[k * 64 + j];
        acc0 = fmaf(hs[q * 4 + 0][k], wv, acc0);
        acc1 = fmaf(hs[q * 4 + 1][k], wv, acc1);
        acc2 = fmaf(hs[q * 4 + 2][k], wv, acc2);
        acc3 = fmaf(hs[q * 4 + 3][k], wv, acc3);
    }
    float dj = d2[j];
    float av[4] = {acc0, acc1, acc2, acc3};
#pragma unroll
    for (int i = 0; i < 4; i++) {
        int n = n0 + q * 4 + i;
        h2[n * 64 + j] = av[i] + dj;
    }
}

// ------- layer-2 gather: 1 wave per node, lane=channel; fused relu+b2+stats -
__global__ __launch_bounds__(256) void k_gather2(const int* __restrict__ row_start,
        const int* __restrict__ cnt, const int2* __restrict__ entries,
        const float* __restrict__ dinv, const float* __restrict__ h2,
        const float* __restrict__ b2, float* __restrict__ out2,
        float* __restrict__ s2, float* __restrict__ q2) {
    int j = threadIdx.x & 63;
    int w = threadIdx.x >> 6;
    float bj = b2[j];
    float ps = 0.f, pq = 0.f;
    for (int n = blockIdx.x * 4 + w; n < N_NODES; n += gridDim.x * 4) {
        int rs = row_start[n], cn = cnt[n];
        float di = dinv[n];
        float acc = h2[n * 64 + j] * di * di;
        const int2* ep = entries + rs;
        int i = 0;
        for (; i + 1 < cn; i += 2) {
            int2 e0 = ep[i], e1 = ep[i + 1];
            float v0 = h2[e0.x * 64 + j];
            float v1 = h2[e1.x * 64 + j];
            acc = fmaf(v0, __int_as_float(e0.y), acc);
            acc = fmaf(v1, __int_as_float(e1.y), acc);
        }
        if (i < cn) {
            int2 e = ep[i];
            acc = fmaf(h2[e.x * 64 + j], __int_as_float(e.y), acc);
        }
        float v = fmaxf(acc + bj, 0.f);
        out2[n * 64 + j] = v;
        ps += v; pq += v * v;
    }
    __shared__ float ssum[64], sq[64];
    if (threadIdx.x < 64) { ssum[threadIdx.x] = 0.f; sq[threadIdx.x] = 0.f; }
    __syncthreads();
    atomicAdd(&ssum[j], ps);
    atomicAdd(&sq[j], pq);
    __syncthreads();
    if (threadIdx.x < 64) {
        atomicAdd(&s2[j], ssum[j]);
        atomicAdd(&q2[j], sq[j]);
    }
}

// ---------------- generic BN affine params from stats ----------------
__global__ void k_bnparam(const float* __restrict__ s, const float* __restrict__ q,
                          const float* __restrict__ g, const float* __restrict__ be,
                          float* __restrict__ A, float* __restrict__ C, float inv_cnt) {
    int j = threadIdx.x;
    float mean = s[j] * inv_cnt;
    float var  = q[j] * inv_cnt - mean * mean;
    float a = rsqrtf(var + BN_EPS) * g[j];
    A[j] = a;
    C[j] = be[j] - mean * a;
}

// ---------------- global_add_pool (batch is sorted: run-accumulate) ---------
__global__ __launch_bounds__(64) void k_pool(const float* __restrict__ out2,
        const int* __restrict__ batch, const float* __restrict__ A2,
        const float* __restrict__ C2, float* __restrict__ hg) {
    int j = threadIdx.x;
    float a = A2[j], c = C2[j];
    int per = (N_NODES + gridDim.x - 1) / gridDim.x;
    int n0 = blockIdx.x * per, n1 = min(n0 + per, N_NODES);
    float acc = 0.f;
    int cur = -1;
    for (int n = n0; n < n1; n++) {
        int g = batch[n];
        float v = fmaf(out2[n * 64 + j], a, c);
        if (g != cur) {
            if (cur >= 0) atomicAdd(&hg[cur * 64 + j], acc);
            cur = g; acc = v;
        } else {
            acc += v;
        }
    }
    if (cur >= 0) atomicAdd(&hg[cur * 64 + j], acc);
}

// ---------------- fc1 + relu + BN3 stats ----------------
__global__ __launch_bounds__(256) void k_fc1(const float* __restrict__ hg,
        const float* __restrict__ fW1, const float* __restrict__ fb1,
        float* __restrict__ t1, float* __restrict__ s3, float* __restrict__ q3) {
    __shared__ float w[64 * 64];
    int tid = threadIdx.x;
    for (int i = tid; i < 4096; i += 256) w[i] = fW1[i];
    __syncthreads();
    int j = tid & 63, q = tid >> 6;
    float bj = fb1[j];
    float ps = 0.f, pq = 0.f;
    for (int r = blockIdx.x * 4 + q; r < NGRAPH; r += gridDim.x * 4) {
        float acc = bj;
        for (int k = 0; k < 64; k++) acc = fmaf(hg[r * 64 + k], w[k * 64 + j], acc);
        acc = fmaxf(acc, 0.f);
        t1[r * 64 + j] = acc;
        ps += acc; pq += acc * acc;
    }
    atomicAdd(&s3[j], ps);
    atomicAdd(&q3[j], pq);
}

// ---------------- bn3 -> fc2 + relu -> fc3 -> log_softmax ----------------
__global__ __launch_bounds__(256) void k_final(const float* __restrict__ t1,
        const float* __restrict__ A3, const float* __restrict__ C3,
        const float* __restrict__ fW2, const float* __restrict__ fb2,
        const float* __restrict__ fW3, const float* __restrict__ fb3,
        float* __restrict__ out) {
    __shared__ float w2[64 * 64];
    __shared__ float w3s[192];
    __shared__ float a3[64], c3[64], b3s[3];
    int tid = threadIdx.x;
    for (int i = tid; i < 4096; i += 256) w2[i] = fW2[i];
    if (tid < 192) w3s[tid] = fW3[tid];
    if (tid < 64) { a3[tid] = A3[tid]; c3[tid] = C3[tid]; }
    if (tid < 3)  b3s[tid] = fb3[tid];
    __syncthreads();
    int lane = tid & 63, wv = tid >> 6;
    float fbj = fb2[lane];
    for (int r = blockIdx.x * 4 + wv; r < NGRAPH; r += gridDim.x * 4) {
        float acc = fbj;
        for (int k = 0; k < 64; k++) {
            float xk = fmaf(t1[r * 64 + k], a3[k], c3[k]);
            acc = fmaf(xk, w2[k * 64 + lane], acc);
        }
        acc = fmaxf(acc, 0.f);
        float o0 = acc * w3s[lane * 3 + 0];
        float o1 = acc * w3s[lane * 3 + 1];
        float o2 = acc * w3s[lane * 3 + 2];
        for (int off = 32; off; off >>= 1) {
            o0 += __shfl_down(o0, off);
            o1 += __shfl_down(o1, off);
            o2 += __shfl_down(o2, off);
        }
        if (lane == 0) {
            o0 += b3s[0]; o1 += b3s[1]; o2 += b3s[2];
            float m = fmaxf(o0, fmaxf(o1, o2));
            float lse = m + logf(expf(o0 - m) + expf(o1 - m) + expf(o2 - m));
            out[r * 3 + 0] = o0 - lse;
            out[r * 3 + 1] = o1 - lse;
            out[r * 3 + 2] = o2 - lse;
        }
    }
}

extern "C" void kernel_launch(void* const* d_in, const int* in_sizes, int n_in,
                              void* d_out, int out_size, void* d_ws, size_t ws_size,
                              hipStream_t stream) {
    const float* x   = (const float*)d_in[0];
    const int*   ei  = (const int*)d_in[1];
    const int*   bat = (const int*)d_in[2];
    const float* W1  = (const float*)d_in[3];
    const float* b1  = (const float*)d_in[4];
    const float* g1  = (const float*)d_in[5];
    const float* be1 = (const float*)d_in[6];
    const float* W2  = (const float*)d_in[7];
    const float* b2  = (const float*)d_in[8];
    const float* g2  = (const float*)d_in[9];
    const float* be2 = (const float*)d_in[10];
    const float* fW1 = (const float*)d_in[11];
    const float* fb1 = (const float*)d_in[12];
    const float* g3  = (const float*)d_in[13];
    const float* be3 = (const float*)d_in[14];
    const float* fW2 = (const float*)d_in[15];
    const float* fb2 = (const float*)d_in[16];
    const float* fW3 = (const float*)d_in[17];
    const float* fb3 = (const float*)d_in[18];

    // ---- workspace layout ----
    // zeroed region: cnt | cursor | hg | s1 q1 s2 q2 s3 q3
    int*   cnt    = (int*)d_ws;                       // N
    int*   cursor = cnt + N_NODES;                    // N
    float* hg     = (float*)(cursor + N_NODES);       // 512*64
    float* s1     = hg + NGRAPH * 64;                 // 128
    float* q1     = s1 + 128;                         // 128
    float* s2     = q1 + 128;                         // 64
    float* q2     = s2 + 64;                          // 64
    float* s3     = q2 + 64;                          // 64
    float* q3     = s3 + 64;                          // 64
    size_t zero_bytes = ((size_t)N_NODES * 2 + NGRAPH * 64 + 512) * 4;
    // non-zeroed scratch
    float* dinv   = q3 + 64;                          // N
    int*   row_start = (int*)(dinv + N_NODES);        // N
    int*   slocal = row_start + N_NODES;              // N   (scan locals)
    int*   sbsum  = slocal + N_NODES;                 // SCAN_BLOCKS (pad 256)
    int2*  entries = (int2*)(sbsum + 256);            // E (8B each)
    float* aggx   = (float*)(entries + N_EDGES);      // N*4 (16B aligned)
    float* h2     = aggx + (size_t)N_NODES * 4;       // N*64
    float* out2   = h2 + (size_t)N_NODES * 64;        // N*64
    float* W2f    = out2 + (size_t)N_NODES * 64;      // 128*64
    float* d2     = W2f + 128 * 64;                   // 64
    float* A2     = d2 + 64;                          // 64
    float* C2     = A2 + 64;                          // 64
    float* A3     = C2 + 64;                          // 64
    float* C3     = A3 + 64;                          // 64
    float* t1     = C3 + 64;                          // 512*64

    hipMemsetAsync(d_ws, 0, zero_bytes, stream);

    const int* src = ei;
    const int* dst = ei + N_EDGES;

    k_deg    <<<(N_EDGES + 255) / 256, 256, 0, stream>>>(dst, cnt);
    k_scanA  <<<SCAN_BLOCKS, 256, 0, stream>>>(cnt, dinv, slocal, sbsum);
    k_scanB  <<<1, 256, 0, stream>>>(sbsum);
    k_scanC  <<<SCAN_BLOCKS, 256, 0, stream>>>(slocal, sbsum, row_start);
    k_fill   <<<(N_EDGES + 255) / 256, 256, 0, stream>>>(src, dst, row_start, cursor, dinv, entries);
    k_gather1<<<(N_NODES + 255) / 256, 256, 0, stream>>>(row_start, cnt, entries, dinv, (const float4*)x, (float4*)aggx);
    k_stats1 <<<512, 128, 0, stream>>>((const float4*)aggx, W1, b1, s1, q1);
    k_fold1  <<<1, 128, 0, stream>>>(s1, q1, g1, be1, W2, W2f, d2);
    k_h2     <<<N_NODES / 16, 256, 0, stream>>>((const float4*)aggx, W1, b1, W2f, d2, h2);
    k_gather2<<<2048, 256, 0, stream>>>(row_start, cnt, entries, dinv, h2, b2, out2, s2, q2);
    k_bnparam<<<1, 64, 0, stream>>>(s2, q2, g2, be2, A2, C2, 1.0f / (float)N_NODES);
    k_pool   <<<1024, 64, 0, stream>>>(out2, bat, A2, C2, hg);
    k_fc1    <<<16, 256, 0, stream>>>(hg, fW1, fb1, t1, s3, q3);
    k_bnparam<<<1, 64, 0, stream>>>(s3, q3, g3, be3, A3, C3, 1.0f / (float)NGRAPH);
    k_final  <<<16, 256, 0, stream>>>(t1, A3, C3, fW2, fb2, fW3, fb3, (float*)d_out);
}

// Round 4
// 296.748 us; speedup vs baseline: 3.6297x; 1.0407x over previous
//
#include <hip/hip_runtime.h>
#include <hip/hip_fp16.h>
#include <math.h>

#define N_NODES 50000
#define N_EDGES 800000
#define NGRAPH  512
#define BN_EPS  1e-5f
#define SCAN_BLOCKS 196   // ceil(50000/256)

// ---------------- degree count (int) ----------------
__global__ void k_deg(const int* __restrict__ dst, int* __restrict__ cnt) {
    int e = blockIdx.x * blockDim.x + threadIdx.x;
    if (e < N_EDGES) atomicAdd(&cnt[dst[e]], 1);
}

// ------- scan A: per-256-chunk exclusive scan (coalesced) + dinv fused ------
__global__ __launch_bounds__(256) void k_scanA(const int* __restrict__ cnt,
        float* __restrict__ dinv, int* __restrict__ local, int* __restrict__ bsum) {
    int t = threadIdx.x;
    int n = blockIdx.x * 256 + t;
    int v = 0;
    if (n < N_NODES) {
        v = cnt[n];
        dinv[n] = rsqrtf((float)v + 1.0f);
    }
    __shared__ int sh[256];
    sh[t] = v;
    __syncthreads();
    for (int off = 1; off < 256; off <<= 1) {
        int u = (t >= off) ? sh[t - off] : 0;
        __syncthreads();
        sh[t] += u;
        __syncthreads();
    }
    if (n < N_NODES) local[n] = sh[t] - v;
    if (t == 255) bsum[blockIdx.x] = sh[255];
}

// ------- scan B: exclusive scan of 196 block sums (1 tiny block) ------
__global__ __launch_bounds__(256) void k_scanB(int* __restrict__ bsum) {
    int t = threadIdx.x;
    int v = (t < SCAN_BLOCKS) ? bsum[t] : 0;
    __shared__ int sh[256];
    sh[t] = v;
    __syncthreads();
    for (int off = 1; off < 256; off <<= 1) {
        int u = (t >= off) ? sh[t - off] : 0;
        __syncthreads();
        sh[t] += u;
        __syncthreads();
    }
    if (t < SCAN_BLOCKS) bsum[t] = sh[t] - v;   // exclusive block offsets
}

// ------- scan C: row_start = local + block offset ------
__global__ void k_scanC(const int* __restrict__ local, const int* __restrict__ bsum,
                        int* __restrict__ row_start) {
    int n = blockIdx.x * blockDim.x + threadIdx.x;
    if (n < N_NODES) row_start[n] = local[n] + bsum[n >> 8];
}

// ---------------- CSR fill: entry = {src, coef} ----------------
__global__ void k_fill(const int* __restrict__ src, const int* __restrict__ dst,
                       const int* __restrict__ row_start, int* __restrict__ cursor,
                       const float* __restrict__ dinv, int2* __restrict__ entries) {
    int e = blockIdx.x * blockDim.x + threadIdx.x;
    if (e >= N_EDGES) return;
    int s = src[e], t = dst[e];
    int pos = row_start[t] + atomicAdd(&cursor[t], 1);
    entries[pos] = make_int2(s, __float_as_int(dinv[s] * dinv[t]));
}

// ---------------- layer-1 gather (4 channels) + self term ----------------
__global__ void k_gather1(const int* __restrict__ row_start, const int* __restrict__ cnt,
                          const int2* __restrict__ entries, const float* __restrict__ dinv,
                          const float4* __restrict__ x, float4* __restrict__ aggx) {
    int n = blockIdx.x * blockDim.x + threadIdx.x;
    if (n >= N_NODES) return;
    float di = dinv[n], c = di * di;
    float4 a = x[n];
    float4 acc = make_float4(a.x * c, a.y * c, a.z * c, a.w * c);
    int rs = row_start[n], cn = cnt[n];
    const int2* ep = entries + rs;
    for (int i = 0; i < cn; i++) {
        int2 e = ep[i];
        float co = __int_as_float(e.y);
        float4 v = x[e.x];
        acc.x = fmaf(v.x, co, acc.x);
        acc.y = fmaf(v.y, co, acc.y);
        acc.z = fmaf(v.z, co, acc.z);
        acc.w = fmaf(v.w, co, acc.w);
    }
    aggx[n] = acc;
}

// ---------------- BN1 stats (h1 recomputed on the fly, never stored) --------
__global__ __launch_bounds__(128) void k_stats1(const float4* __restrict__ aggx,
        const float* __restrict__ W1, const float* __restrict__ b1,
        float* __restrict__ s1, float* __restrict__ q1) {
    __shared__ float w1s[4][128];
    int j = threadIdx.x;
    for (int c = 0; c < 4; c++) w1s[c][j] = W1[c * 128 + j];
    float bj = b1[j];
    __syncthreads();
    int per = (N_NODES + gridDim.x - 1) / gridDim.x;
    int n0 = blockIdx.x * per, n1 = min(n0 + per, N_NODES);
    float ps = 0.f, pq = 0.f;
    for (int n = n0; n < n1; n++) {
        float4 a = aggx[n];
        float h = fmaf(a.x, w1s[0][j], fmaf(a.y, w1s[1][j],
                  fmaf(a.z, w1s[2][j], fmaf(a.w, w1s[3][j], bj))));
        h = fmaxf(h, 0.f);
        ps += h; pq += h * h;
    }
    atomicAdd(&s1[j], ps);
    atomicAdd(&q1[j], pq);
}

// ---------------- fold BN1 into W2 -> W2f, d2 ----------------
__global__ __launch_bounds__(128) void k_fold1(const float* __restrict__ s1,
        const float* __restrict__ q1, const float* __restrict__ g1,
        const float* __restrict__ be1, const float* __restrict__ W2,
        float* __restrict__ W2f, float* __restrict__ d2) {
    __shared__ float a[128], c[128];
    int t = threadIdx.x;
    {
        float mean = s1[t] / (float)N_NODES;
        float var  = q1[t] / (float)N_NODES - mean * mean;
        float aa   = rsqrtf(var + BN_EPS) * g1[t];
        a[t] = aa;
        c[t] = be1[t] - mean * aa;
    }
    __syncthreads();
    if (t < 64) {
        float dd = 0.f;
        for (int k = 0; k < 128; k++) {
            float wv = W2[k * 64 + t];
            W2f[k * 64 + t] = a[k] * wv;
            dd = fmaf(c[k], wv, dd);
        }
        d2[t] = dd;
    }
}

// ------- fused: recompute h1 tile from aggx, GEMM vs W2f -> h2 (fp16) ----
__global__ __launch_bounds__(256) void k_h2(const float4* __restrict__ aggx,
        const float* __restrict__ W1, const float* __restrict__ b1,
        const float* __restrict__ W2f, const float* __restrict__ d2,
        __half* __restrict__ h2) {
    __shared__ float w[128 * 64];
    __shared__ float hs[16][128];
    __shared__ float w1s[4][128];
    __shared__ float b1s[128];
    int tid = threadIdx.x;
    for (int i = tid; i < 8192; i += 256) w[i] = W2f[i];
    if (tid < 128) {
        b1s[tid] = b1[tid];
        for (int c = 0; c < 4; c++) w1s[c][tid] = W1[c * 128 + tid];
    }
    __syncthreads();
    int n0 = blockIdx.x * 16;   // grid is exactly N_NODES/16
    for (int i = tid; i < 2048; i += 256) {
        int nn = n0 + (i >> 7), j = i & 127;
        float4 a = aggx[nn];
        float h = fmaf(a.x, w1s[0][j], fmaf(a.y, w1s[1][j],
                  fmaf(a.z, w1s[2][j], fmaf(a.w, w1s[3][j], b1s[j]))));
        hs[i >> 7][j] = fmaxf(h, 0.f);
    }
    __syncthreads();
    int j = tid & 63, q = tid >> 6;
    float acc0 = 0.f, acc1 = 0.f, acc2 = 0.f, acc3 = 0.f;
    for (int k = 0; k < 128; k++) {
        float wv = w[k * 64 + j];
        acc0 = fmaf(hs[q * 4 + 0][k], wv, acc0);
        acc1 = fmaf(hs[q * 4 + 1][k], wv, acc1);
        acc2 = fmaf(hs[q * 4 + 2][k], wv, acc2);
        acc3 = fmaf(hs[q * 4 + 3][k], wv, acc3);
    }
    float dj = d2[j];
    float av[4] = {acc0, acc1, acc2, acc3};
#pragma unroll
    for (int i = 0; i < 4; i++) {
        int n = n0 + q * 4 + i;
        h2[n * 64 + j] = __float2half(av[i] + dj);
    }
}

// ------- layer-2 gather: 1 wave/node, lane=channel, wave-coop entry loads ---
__global__ __launch_bounds__(256) void k_gather2(const int* __restrict__ row_start,
        const int* __restrict__ cnt, const int2* __restrict__ entries,
        const float* __restrict__ dinv, const __half* __restrict__ h2,
        const float* __restrict__ b2, __half* __restrict__ out2,
        float* __restrict__ s2, float* __restrict__ q2) {
    int j = threadIdx.x & 63;       // lane = channel
    int w = threadIdx.x >> 6;
    float bj = b2[j];
    float ps = 0.f, pq = 0.f;
    for (int n = blockIdx.x * 4 + w; n < N_NODES; n += gridDim.x * 4) {
        int rs = row_start[n], cn = cnt[n];
        float di = dinv[n];
        float acc = __half2float(h2[n * 64 + j]) * di * di;
        const int2* ep = entries + rs;
        int i = 0;
        while (i < cn) {
            int m = min(64, cn - i);
            int2 e = (j < m) ? ep[i + j] : make_int2(0, 0);
            int k = 0;
            for (; k + 1 < m; k += 2) {
                int s0 = __shfl(e.x, k);
                int s1 = __shfl(e.x, k + 1);
                float c0 = __int_as_float(__shfl(e.y, k));
                float c1 = __int_as_float(__shfl(e.y, k + 1));
                float v0 = __half2float(h2[s0 * 64 + j]);
                float v1 = __half2float(h2[s1 * 64 + j]);
                acc = fmaf(v0, c0, acc);
                acc = fmaf(v1, c1, acc);
            }
            if (k < m) {
                int s0 = __shfl(e.x, k);
                float c0 = __int_as_float(__shfl(e.y, k));
                acc = fmaf(__half2float(h2[s0 * 64 + j]), c0, acc);
            }
            i += m;
        }
        float v = fmaxf(acc + bj, 0.f);
        out2[n * 64 + j] = __float2half(v);
        ps += v; pq += v * v;
    }
    __shared__ float ssum[64], sq[64];
    if (threadIdx.x < 64) { ssum[threadIdx.x] = 0.f; sq[threadIdx.x] = 0.f; }
    __syncthreads();
    atomicAdd(&ssum[j], ps);
    atomicAdd(&sq[j], pq);
    __syncthreads();
    if (threadIdx.x < 64) {
        atomicAdd(&s2[j], ssum[j]);
        atomicAdd(&q2[j], sq[j]);
    }
}

// ---------------- generic BN affine params from stats ----------------
__global__ void k_bnparam(const float* __restrict__ s, const float* __restrict__ q,
                          const float* __restrict__ g, const float* __restrict__ be,
                          float* __restrict__ A, float* __restrict__ C, float inv_cnt) {
    int j = threadIdx.x;
    float mean = s[j] * inv_cnt;
    float var  = q[j] * inv_cnt - mean * mean;
    float a = rsqrtf(var + BN_EPS) * g[j];
    A[j] = a;
    C[j] = be[j] - mean * a;
}

// ---------------- global_add_pool (batch is sorted: run-accumulate) ---------
__global__ __launch_bounds__(64) void k_pool(const __half* __restrict__ out2,
        const int* __restrict__ batch, const float* __restrict__ A2,
        const float* __restrict__ C2, float* __restrict__ hg) {
    int j = threadIdx.x;
    float a = A2[j], c = C2[j];
    int per = (N_NODES + gridDim.x - 1) / gridDim.x;
    int n0 = blockIdx.x * per, n1 = min(n0 + per, N_NODES);
    float acc = 0.f;
    int cur = -1;
    for (int n = n0; n < n1; n++) {
        int g = batch[n];
        float v = fmaf(__half2float(out2[n * 64 + j]), a, c);
        if (g != cur) {
            if (cur >= 0) atomicAdd(&hg[cur * 64 + j], acc);
            cur = g; acc = v;
        } else {
            acc += v;
        }
    }
    if (cur >= 0) atomicAdd(&hg[cur * 64 + j], acc);
}

// ---------------- fc1 + relu + BN3 stats ----------------
__global__ __launch_bounds__(256) void k_fc1(const float* __restrict__ hg,
        const float* __restrict__ fW1, const float* __restrict__ fb1,
        float* __restrict__ t1, float* __restrict__ s3, float* __restrict__ q3) {
    __shared__ float w[64 * 64];
    int tid = threadIdx.x;
    for (int i = tid; i < 4096; i += 256) w[i] = fW1[i];
    __syncthreads();
    int j = tid & 63, q = tid >> 6;
    float bj = fb1[j];
    float ps = 0.f, pq = 0.f;
    for (int r = blockIdx.x * 4 + q; r < NGRAPH; r += gridDim.x * 4) {
        float acc = bj;
        for (int k = 0; k < 64; k++) acc = fmaf(hg[r * 64 + k], w[k * 64 + j], acc);
        acc = fmaxf(acc, 0.f);
        t1[r * 64 + j] = acc;
        ps += acc; pq += acc * acc;
    }
    atomicAdd(&s3[j], ps);
    atomicAdd(&q3[j], pq);
}

// ---------------- bn3 -> fc2 + relu -> fc3 -> log_softmax ----------------
__global__ __launch_bounds__(256) void k_final(const float* __restrict__ t1,
        const float* __restrict__ A3, const float* __restrict__ C3,
        const float* __restrict__ fW2, const float* __restrict__ fb2,
        const float* __restrict__ fW3, const float* __restrict__ fb3,
        float* __restrict__ out) {
    __shared__ float w2[64 * 64];
    __shared__ float w3s[192];
    __shared__ float a3[64], c3[64], b3s[3];
    int tid = threadIdx.x;
    for (int i = tid; i < 4096; i += 256) w2[i] = fW2[i];
    if (tid < 192) w3s[tid] = fW3[tid];
    if (tid < 64) { a3[tid] = A3[tid]; c3[tid] = C3[tid]; }
    if (tid < 3)  b3s[tid] = fb3[tid];
    __syncthreads();
    int lane = tid & 63, wv = tid >> 6;
    float fbj = fb2[lane];
    for (int r = blockIdx.x * 4 + wv; r < NGRAPH; r += gridDim.x * 4) {
        float acc = fbj;
        for (int k = 0; k < 64; k++) {
            float xk = fmaf(t1[r * 64 + k], a3[k], c3[k]);
            acc = fmaf(xk, w2[k * 64 + lane], acc);
        }
        acc = fmaxf(acc, 0.f);
        float o0 = acc * w3s[lane * 3 + 0];
        float o1 = acc * w3s[lane * 3 + 1];
        float o2 = acc * w3s[lane * 3 + 2];
        for (int off = 32; off; off >>= 1) {
            o0 += __shfl_down(o0, off);
            o1 += __shfl_down(o1, off);
            o2 += __shfl_down(o2, off);
        }
        if (lane == 0) {
            o0 += b3s[0]; o1 += b3s[1]; o2 += b3s[2];
            float m = fmaxf(o0, fmaxf(o1, o2));
            float lse = m + logf(expf(o0 - m) + expf(o1 - m) + expf(o2 - m));
            out[r * 3 + 0] = o0 - lse;
            out[r * 3 + 1] = o1 - lse;
            out[r * 3 + 2] = o2 - lse;
        }
    }
}

extern "C" void kernel_launch(void* const* d_in, const int* in_sizes, int n_in,
                              void* d_out, int out_size, void* d_ws, size_t ws_size,
                              hipStream_t stream) {
    const float* x   = (const float*)d_in[0];
    const int*   ei  = (const int*)d_in[1];
    const int*   bat = (const int*)d_in[2];
    const float* W1  = (const float*)d_in[3];
    const float* b1  = (const float*)d_in[4];
    const float* g1  = (const float*)d_in[5];
    const float* be1 = (const float*)d_in[6];
    const float* W2  = (const float*)d_in[7];
    const float* b2  = (const float*)d_in[8];
    const float* g2  = (const float*)d_in[9];
    const float* be2 = (const float*)d_in[10];
    const float* fW1 = (const float*)d_in[11];
    const float* fb1 = (const float*)d_in[12];
    const float* g3  = (const float*)d_in[13];
    const float* be3 = (const float*)d_in[14];
    const float* fW2 = (const float*)d_in[15];
    const float* fb2 = (const float*)d_in[16];
    const float* fW3 = (const float*)d_in[17];
    const float* fb3 = (const float*)d_in[18];

    // ---- workspace layout ----
    // zeroed region: cnt | cursor | hg | s1 q1 s2 q2 s3 q3
    int*   cnt    = (int*)d_ws;                       // N
    int*   cursor = cnt + N_NODES;                    // N
    float* hg     = (float*)(cursor + N_NODES);       // 512*64
    float* s1     = hg + NGRAPH * 64;                 // 128
    float* q1     = s1 + 128;                         // 128
    float* s2     = q1 + 128;                         // 64
    float* q2     = s2 + 64;                          // 64
    float* s3     = q2 + 64;                          // 64
    float* q3     = s3 + 64;                          // 64
    size_t zero_bytes = ((size_t)N_NODES * 2 + NGRAPH * 64 + 512) * 4;
    // non-zeroed scratch
    float* dinv   = q3 + 64;                          // N
    int*   row_start = (int*)(dinv + N_NODES);        // N
    int*   slocal = row_start + N_NODES;              // N   (scan locals)
    int*   sbsum  = slocal + N_NODES;                 // SCAN_BLOCKS (pad 256)
    int2*  entries = (int2*)(sbsum + 256);            // E (8B each)
    float* aggx   = (float*)(entries + N_EDGES);      // N*4 (16B aligned)
    __half* h2    = (__half*)(aggx + (size_t)N_NODES * 4);   // N*64 halfs
    __half* out2  = h2 + (size_t)N_NODES * 64;        // N*64 halfs
    float* W2f    = (float*)(out2 + (size_t)N_NODES * 64);   // 128*64
    float* d2     = W2f + 128 * 64;                   // 64
    float* A2     = d2 + 64;                          // 64
    float* C2     = A2 + 64;                          // 64
    float* A3     = C2 + 64;                          // 64
    float* C3     = A3 + 64;                          // 64
    float* t1     = C3 + 64;                          // 512*64

    hipMemsetAsync(d_ws, 0, zero_bytes, stream);

    const int* src = ei;
    const int* dst = ei + N_EDGES;

    k_deg    <<<(N_EDGES + 255) / 256, 256, 0, stream>>>(dst, cnt);
    k_scanA  <<<SCAN_BLOCKS, 256, 0, stream>>>(cnt, dinv, slocal, sbsum);
    k_scanB  <<<1, 256, 0, stream>>>(sbsum);
    k_scanC  <<<SCAN_BLOCKS, 256, 0, stream>>>(slocal, sbsum, row_start);
    k_fill   <<<(N_EDGES + 255) / 256, 256, 0, stream>>>(src, dst, row_start, cursor, dinv, entries);
    k_gather1<<<(N_NODES + 255) / 256, 256, 0, stream>>>(row_start, cnt, entries, dinv, (const float4*)x, (float4*)aggx);
    k_stats1 <<<512, 128, 0, stream>>>((const float4*)aggx, W1, b1, s1, q1);
    k_fold1  <<<1, 128, 0, stream>>>(s1, q1, g1, be1, W2, W2f, d2);
    k_h2     <<<N_NODES / 16, 256, 0, stream>>>((const float4*)aggx, W1, b1, W2f, d2, h2);
    k_gather2<<<2048, 256, 0, stream>>>(row_start, cnt, entries, dinv, h2, b2, out2, s2, q2);
    k_bnparam<<<1, 64, 0, stream>>>(s2, q2, g2, be2, A2, C2, 1.0f / (float)N_NODES);
    k_pool   <<<1024, 64, 0, stream>>>(out2, bat, A2, C2, hg);
    k_fc1    <<<16, 256, 0, stream>>>(hg, fW1, fb1, t1, s3, q3);
    k_bnparam<<<1, 64, 0, stream>>>(s3, q3, g3, be3, A3, C3, 1.0f / (float)NGRAPH);
    k_final  <<<16, 256, 0, stream>>>(t1, A3, C3, fW2, fb2, fW3, fb3, (float*)d_out);
}

// Round 5
// 289.915 us; speedup vs baseline: 3.7153x; 1.0236x over previous
//
#include <hip/hip_runtime.h>
#include <hip/hip_fp16.h>
#include <math.h>

#define N_NODES 50000
#define N_EDGES 800000
#define NGRAPH  512
#define BN_EPS  1e-5f
#define SCAN_BLOCKS 196   // ceil(50000/256)

// ---------------- degree count (int) ----------------
__global__ void k_deg(const int* __restrict__ dst, int* __restrict__ cnt) {
    int e = blockIdx.x * blockDim.x + threadIdx.x;
    if (e < N_EDGES) atomicAdd(&cnt[dst[e]], 1);
}

// ------- scan A: per-256-chunk exclusive scan (coalesced) + dinv fused ------
__global__ __launch_bounds__(256) void k_scanA(const int* __restrict__ cnt,
        float* __restrict__ dinv, int* __restrict__ local, int* __restrict__ bsum) {
    int t = threadIdx.x;
    int n = blockIdx.x * 256 + t;
    int v = 0;
    if (n < N_NODES) {
        v = cnt[n];
        dinv[n] = rsqrtf((float)v + 1.0f);
    }
    __shared__ int sh[256];
    sh[t] = v;
    __syncthreads();
    for (int off = 1; off < 256; off <<= 1) {
        int u = (t >= off) ? sh[t - off] : 0;
        __syncthreads();
        sh[t] += u;
        __syncthreads();
    }
    if (n < N_NODES) local[n] = sh[t] - v;
    if (t == 255) bsum[blockIdx.x] = sh[255];
}

// ------- scan B: exclusive scan of 196 block sums (1 tiny block) ------
__global__ __launch_bounds__(256) void k_scanB(int* __restrict__ bsum) {
    int t = threadIdx.x;
    int v = (t < SCAN_BLOCKS) ? bsum[t] : 0;
    __shared__ int sh[256];
    sh[t] = v;
    __syncthreads();
    for (int off = 1; off < 256; off <<= 1) {
        int u = (t >= off) ? sh[t - off] : 0;
        __syncthreads();
        sh[t] += u;
        __syncthreads();
    }
    if (t < SCAN_BLOCKS) bsum[t] = sh[t] - v;   // exclusive block offsets
}

// ------- scan C: row_start = local + block offset ------
__global__ void k_scanC(const int* __restrict__ local, const int* __restrict__ bsum,
                        int* __restrict__ row_start) {
    int n = blockIdx.x * blockDim.x + threadIdx.x;
    if (n < N_NODES) row_start[n] = local[n] + bsum[n >> 8];
}

// ---------------- CSR fill: entry = {src, coef} ----------------
__global__ void k_fill(const int* __restrict__ src, const int* __restrict__ dst,
                       const int* __restrict__ row_start, int* __restrict__ cursor,
                       const float* __restrict__ dinv, int2* __restrict__ entries) {
    int e = blockIdx.x * blockDim.x + threadIdx.x;
    if (e >= N_EDGES) return;
    int s = src[e], t = dst[e];
    int pos = row_start[t] + atomicAdd(&cursor[t], 1);
    entries[pos] = make_int2(s, __float_as_int(dinv[s] * dinv[t]));
}

// ---------------- layer-1 gather (4 channels) + self term ----------------
__global__ void k_gather1(const int* __restrict__ row_start, const int* __restrict__ cnt,
                          const int2* __restrict__ entries, const float* __restrict__ dinv,
                          const float4* __restrict__ x, float4* __restrict__ aggx) {
    int n = blockIdx.x * blockDim.x + threadIdx.x;
    if (n >= N_NODES) return;
    float di = dinv[n], c = di * di;
    float4 a = x[n];
    float4 acc = make_float4(a.x * c, a.y * c, a.z * c, a.w * c);
    int rs = row_start[n], cn = cnt[n];
    const int2* ep = entries + rs;
    for (int i = 0; i < cn; i++) {
        int2 e = ep[i];
        float co = __int_as_float(e.y);
        float4 v = x[e.x];
        acc.x = fmaf(v.x, co, acc.x);
        acc.y = fmaf(v.y, co, acc.y);
        acc.z = fmaf(v.z, co, acc.z);
        acc.w = fmaf(v.w, co, acc.w);
    }
    aggx[n] = acc;
}

// ---------------- BN1 stats (h1 recomputed on the fly, never stored) --------
__global__ __launch_bounds__(128) void k_stats1(const float4* __restrict__ aggx,
        const float* __restrict__ W1, const float* __restrict__ b1,
        float* __restrict__ s1, float* __restrict__ q1) {
    __shared__ float w1s[4][128];
    int j = threadIdx.x;
    for (int c = 0; c < 4; c++) w1s[c][j] = W1[c * 128 + j];
    float bj = b1[j];
    __syncthreads();
    int per = (N_NODES + gridDim.x - 1) / gridDim.x;
    int n0 = blockIdx.x * per, n1 = min(n0 + per, N_NODES);
    float ps = 0.f, pq = 0.f;
    for (int n = n0; n < n1; n++) {
        float4 a = aggx[n];
        float h = fmaf(a.x, w1s[0][j], fmaf(a.y, w1s[1][j],
                  fmaf(a.z, w1s[2][j], fmaf(a.w, w1s[3][j], bj))));
        h = fmaxf(h, 0.f);
        ps += h; pq += h * h;
    }
    atomicAdd(&s1[j], ps);
    atomicAdd(&q1[j], pq);
}

// ---------------- fold BN1 into W2 -> W2f, d2 ----------------
__global__ __launch_bounds__(128) void k_fold1(const float* __restrict__ s1,
        const float* __restrict__ q1, const float* __restrict__ g1,
        const float* __restrict__ be1, const float* __restrict__ W2,
        float* __restrict__ W2f, float* __restrict__ d2) {
    __shared__ float a[128], c[128];
    int t = threadIdx.x;
    {
        float mean = s1[t] / (float)N_NODES;
        float var  = q1[t] / (float)N_NODES - mean * mean;
        float aa   = rsqrtf(var + BN_EPS) * g1[t];
        a[t] = aa;
        c[t] = be1[t] - mean * aa;
    }
    __syncthreads();
    if (t < 64) {
        float dd = 0.f;
        for (int k = 0; k < 128; k++) {
            float wv = W2[k * 64 + t];
            W2f[k * 64 + t] = a[k] * wv;
            dd = fmaf(c[k], wv, dd);
        }
        d2[t] = dd;
    }
}

// ------- fused: recompute h1 tile from aggx, GEMM vs W2f -> h2 (fp16) ----
__global__ __launch_bounds__(256) void k_h2(const float4* __restrict__ aggx,
        const float* __restrict__ W1, const float* __restrict__ b1,
        const float* __restrict__ W2f, const float* __restrict__ d2,
        __half* __restrict__ h2) {
    __shared__ float w[128 * 64];
    __shared__ float hs[16][128];
    __shared__ float w1s[4][128];
    __shared__ float b1s[128];
    int tid = threadIdx.x;
    for (int i = tid; i < 8192; i += 256) w[i] = W2f[i];
    if (tid < 128) {
        b1s[tid] = b1[tid];
        for (int c = 0; c < 4; c++) w1s[c][tid] = W1[c * 128 + tid];
    }
    __syncthreads();
    int n0 = blockIdx.x * 16;   // grid is exactly N_NODES/16
    for (int i = tid; i < 2048; i += 256) {
        int nn = n0 + (i >> 7), j = i & 127;
        float4 a = aggx[nn];
        float h = fmaf(a.x, w1s[0][j], fmaf(a.y, w1s[1][j],
                  fmaf(a.z, w1s[2][j], fmaf(a.w, w1s[3][j], b1s[j]))));
        hs[i >> 7][j] = fmaxf(h, 0.f);
    }
    __syncthreads();
    int j = tid & 63, q = tid >> 6;
    float acc0 = 0.f, acc1 = 0.f, acc2 = 0.f, acc3 = 0.f;
    for (int k = 0; k < 128; k++) {
        float wv = w[k * 64 + j];
        acc0 = fmaf(hs[q * 4 + 0][k], wv, acc0);
        acc1 = fmaf(hs[q * 4 + 1][k], wv, acc1);
        acc2 = fmaf(hs[q * 4 + 2][k], wv, acc2);
        acc3 = fmaf(hs[q * 4 + 3][k], wv, acc3);
    }
    float dj = d2[j];
    float av[4] = {acc0, acc1, acc2, acc3};
#pragma unroll
    for (int i = 0; i < 4; i++) {
        int n = n0 + q * 4 + i;
        h2[n * 64 + j] = __float2half(av[i] + dj);
    }
}

// ------- layer-2 gather: 2 nodes/wave (32 lanes each, half2/lane),
//         wave-coop entry loads + width-32 shfl broadcast, fused stats -------
__global__ __launch_bounds__(256) void k_gather2(const int* __restrict__ row_start,
        const int* __restrict__ cnt, const int2* __restrict__ entries,
        const float* __restrict__ dinv, const __half2* __restrict__ h2v,
        const float* __restrict__ b2, __half2* __restrict__ out2v,
        float* __restrict__ s2, float* __restrict__ q2) {
    int lane = threadIdx.x & 63;
    int g = lane >> 5;              // 0 = node A, 1 = node B
    int j = lane & 31;              // half2 channel-pair index (ch 2j, 2j+1)
    int wid = blockIdx.x * (blockDim.x >> 6) + (threadIdx.x >> 6);
    int nwaves = gridDim.x * (blockDim.x >> 6);
    float2 bj = make_float2(b2[2 * j], b2[2 * j + 1]);
    float2 ps = make_float2(0.f, 0.f), pq = make_float2(0.f, 0.f);

    for (int base = wid * 2; base < N_NODES; base += nwaves * 2) {
        int n = base + g;
        bool valid = (n < N_NODES);
        int nn = valid ? n : 0;
        int rs = row_start[nn];
        int cn = valid ? cnt[nn] : 0;
        float di = dinv[nn];
        float2 self = __half22float2(h2v[nn * 32 + j]);
        float sc = di * di;
        float2 acc0 = make_float2(self.x * sc, self.y * sc);
        float2 acc1 = make_float2(0.f, 0.f);
        // uniform max count across both half-waves
        int cnO = __shfl(cn, (lane + 32) & 63);
        int cnmax = max(cn, cnO);
        const int2* ep = entries + rs;
        int i = 0;
        while (i < cnmax) {
            int um = min(32, cnmax - i);
            int myRem = min(32, max(0, cn - i));
            int2 e = (j < myRem) ? ep[i + j] : make_int2(0, 0);  // coef bits 0 -> fma no-op
            int k = 0;
            for (; k + 1 < um; k += 2) {
                int s0 = __shfl(e.x, k, 32);
                int s1 = __shfl(e.x, k + 1, 32);
                float c0 = __int_as_float(__shfl(e.y, k, 32));
                float c1 = __int_as_float(__shfl(e.y, k + 1, 32));
                float2 v0 = __half22float2(h2v[s0 * 32 + j]);
                float2 v1 = __half22float2(h2v[s1 * 32 + j]);
                acc0.x = fmaf(v0.x, c0, acc0.x);
                acc0.y = fmaf(v0.y, c0, acc0.y);
                acc1.x = fmaf(v1.x, c1, acc1.x);
                acc1.y = fmaf(v1.y, c1, acc1.y);
            }
            if (k < um) {
                int s0 = __shfl(e.x, k, 32);
                float c0 = __int_as_float(__shfl(e.y, k, 32));
                float2 v0 = __half22float2(h2v[s0 * 32 + j]);
                acc0.x = fmaf(v0.x, c0, acc0.x);
                acc0.y = fmaf(v0.y, c0, acc0.y);
            }
            i += 32;
        }
        if (valid) {
            float vx = fmaxf(acc0.x + acc1.x + bj.x, 0.f);
            float vy = fmaxf(acc0.y + acc1.y + bj.y, 0.f);
            out2v[n * 32 + j] = __floats2half2_rn(vx, vy);
            ps.x += vx; ps.y += vy;
            pq.x += vx * vx; pq.y += vy * vy;
        }
    }
    __shared__ float ssum[64], sq[64];
    if (threadIdx.x < 64) { ssum[threadIdx.x] = 0.f; sq[threadIdx.x] = 0.f; }
    __syncthreads();
    atomicAdd(&ssum[2 * j], ps.x);
    atomicAdd(&ssum[2 * j + 1], ps.y);
    atomicAdd(&sq[2 * j], pq.x);
    atomicAdd(&sq[2 * j + 1], pq.y);
    __syncthreads();
    if (threadIdx.x < 64) {
        atomicAdd(&s2[threadIdx.x], ssum[threadIdx.x]);
        atomicAdd(&q2[threadIdx.x], sq[threadIdx.x]);
    }
}

// ---------------- generic BN affine params from stats ----------------
__global__ void k_bnparam(const float* __restrict__ s, const float* __restrict__ q,
                          const float* __restrict__ g, const float* __restrict__ be,
                          float* __restrict__ A, float* __restrict__ C, float inv_cnt) {
    int j = threadIdx.x;
    float mean = s[j] * inv_cnt;
    float var  = q[j] * inv_cnt - mean * mean;
    float a = rsqrtf(var + BN_EPS) * g[j];
    A[j] = a;
    C[j] = be[j] - mean * a;
}

// ---------------- global_add_pool (batch is sorted: run-accumulate) ---------
__global__ __launch_bounds__(64) void k_pool(const __half* __restrict__ out2,
        const int* __restrict__ batch, const float* __restrict__ A2,
        const float* __restrict__ C2, float* __restrict__ hg) {
    int j = threadIdx.x;
    float a = A2[j], c = C2[j];
    int per = (N_NODES + gridDim.x - 1) / gridDim.x;
    int n0 = blockIdx.x * per, n1 = min(n0 + per, N_NODES);
    float acc = 0.f;
    int cur = -1;
    for (int n = n0; n < n1; n++) {
        int g = batch[n];
        float v = fmaf(__half2float(out2[n * 64 + j]), a, c);
        if (g != cur) {
            if (cur >= 0) atomicAdd(&hg[cur * 64 + j], acc);
            cur = g; acc = v;
        } else {
            acc += v;
        }
    }
    if (cur >= 0) atomicAdd(&hg[cur * 64 + j], acc);
}

// ---------------- fc1 + relu + BN3 stats ----------------
__global__ __launch_bounds__(256) void k_fc1(const float* __restrict__ hg,
        const float* __restrict__ fW1, const float* __restrict__ fb1,
        float* __restrict__ t1, float* __restrict__ s3, float* __restrict__ q3) {
    __shared__ float w[64 * 64];
    int tid = threadIdx.x;
    for (int i = tid; i < 4096; i += 256) w[i] = fW1[i];
    __syncthreads();
    int j = tid & 63, q = tid >> 6;
    float bj = fb1[j];
    float ps = 0.f, pq = 0.f;
    for (int r = blockIdx.x * 4 + q; r < NGRAPH; r += gridDim.x * 4) {
        float acc = bj;
        for (int k = 0; k < 64; k++) acc = fmaf(hg[r * 64 + k], w[k * 64 + j], acc);
        acc = fmaxf(acc, 0.f);
        t1[r * 64 + j] = acc;
        ps += acc; pq += acc * acc;
    }
    atomicAdd(&s3[j], ps);
    atomicAdd(&q3[j], pq);
}

// ---------------- bn3 -> fc2 + relu -> fc3 -> log_softmax ----------------
__global__ __launch_bounds__(256) void k_final(const float* __restrict__ t1,
        const float* __restrict__ A3, const float* __restrict__ C3,
        const float* __restrict__ fW2, const float* __restrict__ fb2,
        const float* __restrict__ fW3, const float* __restrict__ fb3,
        float* __restrict__ out) {
    __shared__ float w2[64 * 64];
    __shared__ float w3s[192];
    __shared__ float a3[64], c3[64], b3s[3];
    int tid = threadIdx.x;
    for (int i = tid; i < 4096; i += 256) w2[i] = fW2[i];
    if (tid < 192) w3s[tid] = fW3[tid];
    if (tid < 64) { a3[tid] = A3[tid]; c3[tid] = C3[tid]; }
    if (tid < 3)  b3s[tid] = fb3[tid];
    __syncthreads();
    int lane = tid & 63, wv = tid >> 6;
    float fbj = fb2[lane];
    for (int r = blockIdx.x * 4 + wv; r < NGRAPH; r += gridDim.x * 4) {
        float acc = fbj;
        for (int k = 0; k < 64; k++) {
            float xk = fmaf(t1[r * 64 + k], a3[k], c3[k]);
            acc = fmaf(xk, w2[k * 64 + lane], acc);
        }
        acc = fmaxf(acc, 0.f);
        float o0 = acc * w3s[lane * 3 + 0];
        float o1 = acc * w3s[lane * 3 + 1];
        float o2 = acc * w3s[lane * 3 + 2];
        for (int off = 32; off; off >>= 1) {
            o0 += __shfl_down(o0, off);
            o1 += __shfl_down(o1, off);
            o2 += __shfl_down(o2, off);
        }
        if (lane == 0) {
            o0 += b3s[0]; o1 += b3s[1]; o2 += b3s[2];
            float m = fmaxf(o0, fmaxf(o1, o2));
            float lse = m + logf(expf(o0 - m) + expf(o1 - m) + expf(o2 - m));
            out[r * 3 + 0] = o0 - lse;
            out[r * 3 + 1] = o1 - lse;
            out[r * 3 + 2] = o2 - lse;
        }
    }
}

extern "C" void kernel_launch(void* const* d_in, const int* in_sizes, int n_in,
                              void* d_out, int out_size, void* d_ws, size_t ws_size,
                              hipStream_t stream) {
    const float* x   = (const float*)d_in[0];
    const int*   ei  = (const int*)d_in[1];
    const int*   bat = (const int*)d_in[2];
    const float* W1  = (const float*)d_in[3];
    const float* b1  = (const float*)d_in[4];
    const float* g1  = (const float*)d_in[5];
    const float* be1 = (const float*)d_in[6];
    const float* W2  = (const float*)d_in[7];
    const float* b2  = (const float*)d_in[8];
    const float* g2  = (const float*)d_in[9];
    const float* be2 = (const float*)d_in[10];
    const float* fW1 = (const float*)d_in[11];
    const float* fb1 = (const float*)d_in[12];
    const float* g3  = (const float*)d_in[13];
    const float* be3 = (const float*)d_in[14];
    const float* fW2 = (const float*)d_in[15];
    const float* fb2 = (const float*)d_in[16];
    const float* fW3 = (const float*)d_in[17];
    const float* fb3 = (const float*)d_in[18];

    // ---- workspace layout ----
    // zeroed region: cnt | cursor | hg | s1 q1 s2 q2 s3 q3
    int*   cnt    = (int*)d_ws;                       // N
    int*   cursor = cnt + N_NODES;                    // N
    float* hg     = (float*)(cursor + N_NODES);       // 512*64
    float* s1     = hg + NGRAPH * 64;                 // 128
    float* q1     = s1 + 128;                         // 128
    float* s2     = q1 + 128;                         // 64
    float* q2     = s2 + 64;                          // 64
    float* s3     = q2 + 64;                          // 64
    float* q3     = s3 + 64;                          // 64
    size_t zero_bytes = ((size_t)N_NODES * 2 + NGRAPH * 64 + 512) * 4;
    // non-zeroed scratch
    float* dinv   = q3 + 64;                          // N
    int*   row_start = (int*)(dinv + N_NODES);        // N
    int*   slocal = row_start + N_NODES;              // N   (scan locals)
    int*   sbsum  = slocal + N_NODES;                 // SCAN_BLOCKS (pad 256)
    int2*  entries = (int2*)(sbsum + 256);            // E (8B each)
    float* aggx   = (float*)(entries + N_EDGES);      // N*4 (16B aligned)
    __half* h2    = (__half*)(aggx + (size_t)N_NODES * 4);   // N*64 halfs
    __half* out2  = h2 + (size_t)N_NODES * 64;        // N*64 halfs
    float* W2f    = (float*)(out2 + (size_t)N_NODES * 64);   // 128*64
    float* d2     = W2f + 128 * 64;                   // 64
    float* A2     = d2 + 64;                          // 64
    float* C2     = A2 + 64;                          // 64
    float* A3     = C2 + 64;                          // 64
    float* C3     = A3 + 64;                          // 64
    float* t1     = C3 + 64;                          // 512*64

    hipMemsetAsync(d_ws, 0, zero_bytes, stream);

    const int* src = ei;
    const int* dst = ei + N_EDGES;

    k_deg    <<<(N_EDGES + 255) / 256, 256, 0, stream>>>(dst, cnt);
    k_scanA  <<<SCAN_BLOCKS, 256, 0, stream>>>(cnt, dinv, slocal, sbsum);
    k_scanB  <<<1, 256, 0, stream>>>(sbsum);
    k_scanC  <<<SCAN_BLOCKS, 256, 0, stream>>>(slocal, sbsum, row_start);
    k_fill   <<<(N_EDGES + 255) / 256, 256, 0, stream>>>(src, dst, row_start, cursor, dinv, entries);
    k_gather1<<<(N_NODES + 255) / 256, 256, 0, stream>>>(row_start, cnt, entries, dinv, (const float4*)x, (float4*)aggx);
    k_stats1 <<<512, 128, 0, stream>>>((const float4*)aggx, W1, b1, s1, q1);
    k_fold1  <<<1, 128, 0, stream>>>(s1, q1, g1, be1, W2, W2f, d2);
    k_h2     <<<N_NODES / 16, 256, 0, stream>>>((const float4*)aggx, W1, b1, W2f, d2, h2);
    k_gather2<<<2048, 256, 0, stream>>>(row_start, cnt, entries, dinv, (const __half2*)h2, b2, (__half2*)out2, s2, q2);
    k_bnparam<<<1, 64, 0, stream>>>(s2, q2, g2, be2, A2, C2, 1.0f / (float)N_NODES);
    k_pool   <<<1024, 64, 0, stream>>>(out2, bat, A2, C2, hg);
    k_fc1    <<<16, 256, 0, stream>>>(hg, fW1, fb1, t1, s3, q3);
    k_bnparam<<<1, 64, 0, stream>>>(s3, q3, g3, be3, A3, C3, 1.0f / (float)NGRAPH);
    k_final  <<<16, 256, 0, stream>>>(t1, A3, C3, fW2, fb2, fW3, fb3, (float*)d_out);
}